// Round 1
// 613.019 us; speedup vs baseline: 1.1228x; 1.1228x over previous
//
#include <hip/hip_runtime.h>
#include <math.h>

// Problem: x:(16,64,256,256) f32 ; wr/wi:(64,64,32,32) f32 ; out:(16,64,256,256) f32
// Pipeline: F1 (DFT-w, 32 modes, MFMA fp16x3) -> F2 (DFT-h) -> M (channel mix) ->
//           I1 (iDFT-h) -> I2 (iDFT-w, MFMA fp16x3, real out).
//
// fp16-split scheme: v_s = 256*v; hi = f16(v_s); lo = f16(v_s - hi).
// A*B approx by hi*hi + lo*hi + hi*lo on mfma_f32_16x16x32_f16; epilogue * 1/(256*256*256)
// (two 256 scale factors + the 1/256 DFT normalization).
//
// Workspace layout (float offsets):
//   e1f_hi: f16[8][4][64][8]  @ 0       (E1 fragments, kt x ntile x lane x j, *256)
//   e1f_lo: f16[...]          @ 8192
//   tt  : [32][256] float2    @ 16384   (cos, sin)
//   e2f_hi: f16[2][16][64][8] @ 32768   (E2 fragments, *256)
//   e2f_lo: f16[...]          @ 40960
//   y  : float2[16][64][256][32] @ 65536
//   xf : float2[16][64][32][32]  @ 16,842,752
//   om : float2[16][64][32][32]  @ 18,939,904
//   g  : aliases y (y dead after F2)

typedef _Float16 f16x4 __attribute__((ext_vector_type(4)));
typedef _Float16 f16x8 __attribute__((ext_vector_type(8)));
typedef float f32x4 __attribute__((ext_vector_type(4)));

__global__ __launch_bounds__(256) void k_tables(float* __restrict__ ws) {
    int idx = blockIdx.x * 256 + threadIdx.x;   // 0..8191
    const float STEP = 6.283185307179586f / 256.f;
    float s, c;
    {   // tt[kx][h] = (cos, sin) of 2*pi*kx*h/256
        int kx = idx >> 8, h = idx & 255;
        int t = (kx * h) & 255;
        sincosf((float)t * STEP, &s, &c);
        ((float2*)(ws + 16384))[kx * 256 + h] = make_float2(c, s);
    }
    _Float16* e1h = (_Float16*)ws;
    _Float16* e1l = (_Float16*)(ws + 8192);
    _Float16* e2h = (_Float16*)(ws + 32768);
    _Float16* e2l = (_Float16*)(ws + 40960);
    if (idx < 2048) {
        // E1 fragments: entry (kt,nt,lane) -> 8 j values.
        // A-frag convention for 16x16x32: k = kt*32 + (lane>>4)*8 + j, col = nt*16 + (lane&15)
        // E1u[k][2ky] = cos(2pi k ky/256), [2ky+1] = -sin(...)  (unscaled), stored *256.
        int l = idx & 63, nt = (idx >> 6) & 3, kt = idx >> 8;
        int col = nt * 16 + (l & 15);
        int ky = col >> 1;
        int kb = kt * 32 + (l >> 4) * 8;
#pragma unroll
        for (int j = 0; j < 8; ++j) {
            int k = kb + j;
            int tt_ = (k * ky) & 255;
            sincosf((float)tt_ * STEP, &s, &c);
            float val = ((col & 1) ? -s : c) * 256.f;
            _Float16 h = (_Float16)val;
            e1h[idx * 8 + j] = h;
            e1l[idx * 8 + j] = (_Float16)(val - (float)h);
        }
    } else if (idx < 4096) {
        // E2 fragments: [kt(2)][nt(16)][lane][8].
        // E2u[2ky][w] = cos(2pi ky w/256), [2ky+1][w] = -sin(...), stored *256.
        // (the (ky?2:1) hermitian factor moved into k_i1's g; 1/256 into k_i2 epilogue)
        int i2 = idx - 2048;
        int l = i2 & 63, nt = (i2 >> 6) & 15, kt = i2 >> 10;
        int w = nt * 16 + (l & 15);
        int kb = kt * 32 + (l >> 4) * 8;
#pragma unroll
        for (int j = 0; j < 8; ++j) {
            int k = kb + j;
            int ky = k >> 1;
            int tt_ = (ky * w) & 255;
            sincosf((float)tt_ * STEP, &s, &c);
            float val = ((k & 1) ? -s : c) * 256.f;
            _Float16 h = (_Float16)val;
            e2h[i2 * 8 + j] = h;
            e2l[i2 * 8 + j] = (_Float16)(val - (float)h);
        }
    }
}

// K1: Y[M=262144][64] = X[M][256] * E1u[256][64] * (1/256).  MFMA fp16x3.
// Block: 256 thr = 4 waves; BM=128 (wave w -> rows w*32..w*32+31), BN=64, BK=32.
__global__ __launch_bounds__(256) void k_f1(const float* __restrict__ x,
                                            const _Float16* __restrict__ e1h,
                                            const _Float16* __restrict__ e1l,
                                            float* __restrict__ y) {
    __shared__ _Float16 Ah[128 * 40];   // row stride 40 halves (80 B) -> 2-way conflicts only
    __shared__ _Float16 Al[128 * 40];
    int t = threadIdx.x, lane = t & 63, wv = t >> 6;
    long row0 = (long)blockIdx.x * 128;
    f32x4 acc[2][4];
#pragma unroll
    for (int m = 0; m < 2; ++m)
#pragma unroll
        for (int n = 0; n < 4; ++n) acc[m][n] = (f32x4){0.f, 0.f, 0.f, 0.f};
    int abase = (wv * 32 + (lane & 15)) * 40 + (lane >> 4) * 8;

    for (int kt = 0; kt < 8; ++kt) {
        // stage A: 128 rows x 32 k, f32 -> (hi,lo) f16, scaled *256
#pragma unroll
        for (int n = 0; n < 4; ++n) {
            int f4 = t + n * 256;
            int r = f4 >> 3, c4 = f4 & 7;
            float4 v = *(const float4*)&x[(row0 + r) * 256 + kt * 32 + c4 * 4];
            float s0 = v.x * 256.f, s1 = v.y * 256.f, s2 = v.z * 256.f, s3 = v.w * 256.f;
            _Float16 h0 = (_Float16)s0, h1 = (_Float16)s1;
            _Float16 h2 = (_Float16)s2, h3 = (_Float16)s3;
            *(f16x4*)&Ah[r * 40 + c4 * 4] = (f16x4){h0, h1, h2, h3};
            *(f16x4*)&Al[r * 40 + c4 * 4] =
                (f16x4){(_Float16)(s0 - (float)h0), (_Float16)(s1 - (float)h1),
                        (_Float16)(s2 - (float)h2), (_Float16)(s3 - (float)h3)};
        }
        __syncthreads();
        f16x8 ah0 = *(const f16x8*)&Ah[abase];
        f16x8 ah1 = *(const f16x8*)&Ah[abase + 16 * 40];
        f16x8 al0 = *(const f16x8*)&Al[abase];
        f16x8 al1 = *(const f16x8*)&Al[abase + 16 * 40];
#pragma unroll
        for (int n = 0; n < 4; ++n) {
            f16x8 bh = *(const f16x8*)(e1h + ((kt * 4 + n) * 64 + lane) * 8);
            f16x8 bl = *(const f16x8*)(e1l + ((kt * 4 + n) * 64 + lane) * 8);
            acc[0][n] = __builtin_amdgcn_mfma_f32_16x16x32_f16(ah0, bh, acc[0][n], 0, 0, 0);
            acc[0][n] = __builtin_amdgcn_mfma_f32_16x16x32_f16(al0, bh, acc[0][n], 0, 0, 0);
            acc[0][n] = __builtin_amdgcn_mfma_f32_16x16x32_f16(ah0, bl, acc[0][n], 0, 0, 0);
            acc[1][n] = __builtin_amdgcn_mfma_f32_16x16x32_f16(ah1, bh, acc[1][n], 0, 0, 0);
            acc[1][n] = __builtin_amdgcn_mfma_f32_16x16x32_f16(al1, bh, acc[1][n], 0, 0, 0);
            acc[1][n] = __builtin_amdgcn_mfma_f32_16x16x32_f16(ah1, bl, acc[1][n], 0, 0, 0);
        }
        __syncthreads();
    }
    const float SC = 1.f / 16777216.f;   // 1/(256 scaleA * 256 scaleB * 256 DFT-norm)
#pragma unroll
    for (int m = 0; m < 2; ++m)
#pragma unroll
        for (int n = 0; n < 4; ++n)
#pragma unroll
            for (int r = 0; r < 4; ++r) {
                long row = row0 + wv * 32 + m * 16 + (lane >> 4) * 4 + r;
                y[row * 64 + n * 16 + (lane & 15)] = acc[m][n][r] * SC;
            }
}

// K2: per batch (b,i): C[64][64] = [Tc;Ts](64x256) * Y(256x64-interleaved)
__global__ __launch_bounds__(256) void k_f2(const float2* __restrict__ tt,
                                            const float2* __restrict__ y,
                                            float2* __restrict__ xf) {
    __shared__ float smem[2176 + 2048];
    float* As = smem;
    float* Bs = smem + 2176;
    int t = threadIdx.x, tx = t & 15, ty = t >> 4;
    int batch = blockIdx.x;
    const float2* ybase = y + (long)batch * 256 * 32;
    float acc[4][4];
#pragma unroll
    for (int i = 0; i < 4; ++i)
#pragma unroll
        for (int j = 0; j < 4; ++j) acc[i][j] = 0.f;

    for (int ht = 0; ht < 8; ++ht) {
        int h0 = ht * 32;
#pragma unroll
        for (int n = 0; n < 4; ++n) {
            int i2 = t + n * 256;
            int kx = i2 >> 5, hh = i2 & 31;
            float2 cs = tt[kx * 256 + h0 + hh];
            As[hh * 68 + kx] = cs.x;
            As[hh * 68 + 32 + kx] = cs.y;
        }
#pragma unroll
        for (int n = 0; n < 4; ++n) {
            int i2 = t + n * 256;
            int hh = i2 >> 5, ky = i2 & 31;
            float2 v = ybase[(h0 + hh) * 32 + ky];
            *(float2*)&Bs[hh * 64 + 2 * ky] = v;
        }
        __syncthreads();
#pragma unroll
        for (int kk = 0; kk < 32; ++kk) {
            float4 a0 = *(const float4*)&As[kk * 68 + ty * 4];
            float4 b0 = *(const float4*)&Bs[kk * 64 + tx * 4];
            float av[4] = {a0.x, a0.y, a0.z, a0.w};
            float bv[4] = {b0.x, b0.y, b0.z, b0.w};
#pragma unroll
            for (int i = 0; i < 4; ++i)
#pragma unroll
                for (int j = 0; j < 4; ++j)
                    acc[i][j] = fmaf(av[i], bv[j], acc[i][j]);
        }
        __syncthreads();
    }
    float* Cs = smem;
#pragma unroll
    for (int i = 0; i < 4; ++i)
#pragma unroll
        for (int j = 0; j < 4; ++j)
            Cs[(ty * 4 + i) * 65 + tx * 4 + j] = acc[i][j];
    __syncthreads();
#pragma unroll
    for (int n = 0; n < 4; ++n) {
        int idx = t + n * 256;
        int kx = idx >> 5, ky = idx & 31;
        float re = Cs[kx * 65 + 2 * ky]     + Cs[(kx + 32) * 65 + 2 * ky + 1];
        float im = Cs[kx * 65 + 2 * ky + 1] - Cs[(kx + 32) * 65 + 2 * ky];
        xf[(long)batch * 1024 + kx * 32 + ky] = make_float2(re, im);
    }
}

// K3: per (b,kx): om[b,o,kx,ky] = sum_i xf[b,i,kx,ky] * (wr+i*wi)[i,o,kx,ky]
__global__ __launch_bounds__(256) void k_mix(const float* __restrict__ wr,
                                             const float* __restrict__ wi,
                                             const float2* __restrict__ xf,
                                             float2* __restrict__ om) {
    __shared__ float2 xs[64 * 32];
    int t = threadIdx.x;
    int b = blockIdx.x >> 5, kx = blockIdx.x & 31;
#pragma unroll
    for (int n = 0; n < 8; ++n) {
        int i2 = t + n * 256;
        int i = i2 >> 5, ky = i2 & 31;
        xs[i2] = xf[(long)(b * 64 + i) * 1024 + kx * 32 + ky];
    }
    __syncthreads();
    int ky = t & 31, og = t >> 5;
    float ar[8], ai[8];
#pragma unroll
    for (int j = 0; j < 8; ++j) { ar[j] = 0.f; ai[j] = 0.f; }
    const float* wrb = wr + kx * 32 + ky;
    const float* wib = wi + kx * 32 + ky;
    for (int i = 0; i < 64; ++i) {
        float2 xv = xs[i * 32 + ky];
#pragma unroll
        for (int j = 0; j < 8; ++j) {
            int o = og * 8 + j;
            long woff = (long)(i * 64 + o) * 1024;
            float wrv = wrb[woff], wiv = wib[woff];
            ar[j] = fmaf(xv.x, wrv, fmaf(-xv.y, wiv, ar[j]));
            ai[j] = fmaf(xv.x, wiv, fmaf(xv.y, wrv, ai[j]));
        }
    }
    float2* omb = om + (long)(b * 64) * 1024 + kx * 32 + ky;
#pragma unroll
    for (int j = 0; j < 8; ++j) {
        int o = og * 8 + j;
        omb[(long)o * 1024] = make_float2(ar[j], ai[j]);
    }
}

// K4: per (b,o) x 4 h-blocks: C[64h][64] = A[64h][64k] * Bm[64k][64]
// g columns now carry the (ky==0?1:2) hermitian factor (1/256 moved to k_i2).
__global__ __launch_bounds__(256) void k_i1(const float2* __restrict__ tt,
                                            const float2* __restrict__ om,
                                            float2* __restrict__ g) {
    __shared__ float As[64 * 68];
    __shared__ float Bs[64 * 64];
    int t = threadIdx.x, tx = t & 15, ty = t >> 4;
    int bo = blockIdx.x >> 2, hb = blockIdx.x & 3;
    int h0 = hb * 64;
#pragma unroll
    for (int n = 0; n < 8; ++n) {
        int i2 = t + n * 256;
        int kx = i2 >> 6, hh = i2 & 63;
        float2 cs = tt[kx * 256 + h0 + hh];
        As[kx * 68 + hh] = cs.x;
        As[(kx + 32) * 68 + hh] = cs.y;
    }
    const float2* ombase = om + (long)bo * 1024;
#pragma unroll
    for (int n = 0; n < 4; ++n) {
        int i2 = t + n * 256;
        int kx = i2 >> 5, ky = i2 & 31;
        float2 v = ombase[kx * 32 + ky];
        Bs[kx * 64 + 2 * ky] = v.x;
        Bs[kx * 64 + 2 * ky + 1] = v.y;
        Bs[(kx + 32) * 64 + 2 * ky] = -v.y;
        Bs[(kx + 32) * 64 + 2 * ky + 1] = v.x;
    }
    __syncthreads();
    float acc[4][4];
#pragma unroll
    for (int i = 0; i < 4; ++i)
#pragma unroll
        for (int j = 0; j < 4; ++j) acc[i][j] = 0.f;
#pragma unroll 16
    for (int k = 0; k < 64; ++k) {
        float4 a0 = *(const float4*)&As[k * 68 + ty * 4];
        float4 b0 = *(const float4*)&Bs[k * 64 + tx * 4];
        float av[4] = {a0.x, a0.y, a0.z, a0.w};
        float bv[4] = {b0.x, b0.y, b0.z, b0.w};
#pragma unroll
        for (int i = 0; i < 4; ++i)
#pragma unroll
            for (int j = 0; j < 4; ++j)
                acc[i][j] = fmaf(av[i], bv[j], acc[i][j]);
    }
    float2* gbase = g + (long)bo * 256 * 32;
    float sa = (tx == 0) ? 1.f : 2.f;   // cols 4tx,4tx+1 -> ky=2tx ; cols 4tx+2,4tx+3 -> ky=2tx+1
#pragma unroll
    for (int i = 0; i < 4; ++i) {
        float4 v = make_float4(acc[i][0] * sa, acc[i][1] * sa, acc[i][2] * 2.f, acc[i][3] * 2.f);
        *(float4*)&gbase[(h0 + ty * 4 + i) * 32 + tx * 2] = v;
    }
}

// K5: out[M=262144][256] = G[M][64] * E2u[64][256] * (1/256).  MFMA fp16x3.
// Block: 256 thr = 4 waves; BM=32, BN=256 (wave w -> cols w*64..w*64+63), K=64 one-shot.
__global__ __launch_bounds__(256) void k_i2(const float* __restrict__ g,
                                            const _Float16* __restrict__ e2h,
                                            const _Float16* __restrict__ e2l,
                                            float* __restrict__ out) {
    __shared__ _Float16 Ah[32 * 72];   // row stride 72 halves (144 B) -> 2-way conflicts only
    __shared__ _Float16 Al[32 * 72];
    int t = threadIdx.x, lane = t & 63, wv = t >> 6;
    long row0 = (long)blockIdx.x * 32;
#pragma unroll
    for (int n = 0; n < 2; ++n) {      // stage A: 32 rows x 64 k
        int f4 = t + n * 256;
        int r = f4 >> 4, c4 = f4 & 15;
        float4 v = *(const float4*)&g[(row0 + r) * 64 + c4 * 4];
        float s0 = v.x * 256.f, s1 = v.y * 256.f, s2 = v.z * 256.f, s3 = v.w * 256.f;
        _Float16 h0 = (_Float16)s0, h1 = (_Float16)s1;
        _Float16 h2 = (_Float16)s2, h3 = (_Float16)s3;
        *(f16x4*)&Ah[r * 72 + c4 * 4] = (f16x4){h0, h1, h2, h3};
        *(f16x4*)&Al[r * 72 + c4 * 4] =
            (f16x4){(_Float16)(s0 - (float)h0), (_Float16)(s1 - (float)h1),
                    (_Float16)(s2 - (float)h2), (_Float16)(s3 - (float)h3)};
    }
    __syncthreads();
    f32x4 acc[2][4];
#pragma unroll
    for (int m = 0; m < 2; ++m)
#pragma unroll
        for (int n = 0; n < 4; ++n) acc[m][n] = (f32x4){0.f, 0.f, 0.f, 0.f};
#pragma unroll
    for (int kt = 0; kt < 2; ++kt) {
        int abase = (lane & 15) * 72 + kt * 32 + (lane >> 4) * 8;
        f16x8 ah0 = *(const f16x8*)&Ah[abase];
        f16x8 ah1 = *(const f16x8*)&Ah[abase + 16 * 72];
        f16x8 al0 = *(const f16x8*)&Al[abase];
        f16x8 al1 = *(const f16x8*)&Al[abase + 16 * 72];
#pragma unroll
        for (int n = 0; n < 4; ++n) {
            int nb = ((kt * 16 + wv * 4 + n) * 64 + lane) * 8;
            f16x8 bh = *(const f16x8*)(e2h + nb);
            f16x8 bl = *(const f16x8*)(e2l + nb);
            acc[0][n] = __builtin_amdgcn_mfma_f32_16x16x32_f16(ah0, bh, acc[0][n], 0, 0, 0);
            acc[0][n] = __builtin_amdgcn_mfma_f32_16x16x32_f16(al0, bh, acc[0][n], 0, 0, 0);
            acc[0][n] = __builtin_amdgcn_mfma_f32_16x16x32_f16(ah0, bl, acc[0][n], 0, 0, 0);
            acc[1][n] = __builtin_amdgcn_mfma_f32_16x16x32_f16(ah1, bh, acc[1][n], 0, 0, 0);
            acc[1][n] = __builtin_amdgcn_mfma_f32_16x16x32_f16(al1, bh, acc[1][n], 0, 0, 0);
            acc[1][n] = __builtin_amdgcn_mfma_f32_16x16x32_f16(ah1, bl, acc[1][n], 0, 0, 0);
        }
    }
    const float SC = 1.f / 16777216.f;   // 1/(256*256*256)
#pragma unroll
    for (int m = 0; m < 2; ++m)
#pragma unroll
        for (int n = 0; n < 4; ++n)
#pragma unroll
            for (int r = 0; r < 4; ++r) {
                long row = row0 + m * 16 + (lane >> 4) * 4 + r;
                out[row * 256 + wv * 64 + n * 16 + (lane & 15)] = acc[m][n][r] * SC;
            }
}

extern "C" void kernel_launch(void* const* d_in, const int* in_sizes, int n_in,
                              void* d_out, int out_size, void* d_ws, size_t ws_size,
                              hipStream_t stream) {
    const float* x  = (const float*)d_in[0];
    const float* wr = (const float*)d_in[1];
    const float* wi = (const float*)d_in[2];
    float* out = (float*)d_out;
    float* ws = (float*)d_ws;

    const _Float16* e1h = (const _Float16*)ws;
    const _Float16* e1l = (const _Float16*)(ws + 8192);
    float2* tt = (float2*)(ws + 16384);
    const _Float16* e2h = (const _Float16*)(ws + 32768);
    const _Float16* e2l = (const _Float16*)(ws + 40960);
    float* y  = ws + 65536;
    float* xf = ws + 65536 + 16777216;
    float* om = ws + 65536 + 16777216 + 2097152;
    float* g  = y;   // alias (y dead after k_f2)

    hipLaunchKernelGGL(k_tables, dim3(32),   dim3(256), 0, stream, ws);
    hipLaunchKernelGGL(k_f1,     dim3(2048), dim3(256), 0, stream, x, e1h, e1l, y);
    hipLaunchKernelGGL(k_f2,     dim3(1024), dim3(256), 0, stream, tt, (const float2*)y, (float2*)xf);
    hipLaunchKernelGGL(k_mix,    dim3(512),  dim3(256), 0, stream, wr, wi, (const float2*)xf, (float2*)om);
    hipLaunchKernelGGL(k_i1,     dim3(4096), dim3(256), 0, stream, tt, (const float2*)om, (float2*)g);
    hipLaunchKernelGGL(k_i2,     dim3(8192), dim3(256), 0, stream, g, e2h, e2l, out);
}

// Round 3
// 607.868 us; speedup vs baseline: 1.1323x; 1.0085x over previous
//
#include <hip/hip_runtime.h>
#include <math.h>

// Problem: x:(16,64,256,256) f32 ; wr/wi:(64,64,32,32) f32 ; out:(16,64,256,256) f32
// Pipeline (big GEMMs on mfma_f32_16x16x32_f16, Markidis split):
//   F1: y[bi][col][h] f32 (=Y_true, transposed)  <- x * E1   (3-term, direct-frag A)
//   F2: xf = T * y        (A from t1 table, B split-at-load x1024, 4-TERM, no LDS staging)
//   M : channel mix (fp32, unchanged)
//   I1: g[bo][h][64] f32 (=herm*z) = Tt * Bm(om x4096)   (4-TERM)
//   I2: out = g * E2      (split-at-load x256, 3-term, no LDS)
//
// Accuracy design: y/g stored exact f32 (same HBM bytes as f16 hi+lo; each read once).
// F2/I1 use 4-term (hh+lh+hl+ll) so their only error is 2^-22-level split repr.
// om split at x4096, y at x1024, g at x256: keeps all lo terms in f16 normal range.
//
// Scale chain:
//   F1: acc = 65536*256*Y -> y = acc/16777216
//   F2: acc = 256(t1)*1024(y) * xf -> xf = acc/262144
//   I1: acc = 256(t2)*4096(om) * z -> g = acc * herm/1048576
//   I2: acc = 256(g)*256(e2) * 256*out -> out = acc/16777216
//
// Workspace (float offsets):
//   e1h/e1l: f16[8][4][64][8]   @ 0 / 8192       (F1 B frags, *256)
//   e2h/e2l: f16[2][16][64][8]  @ 16384 / 24576  (I2 B frags, *256)
//   t1h/t1l: f16[4][8][64][8]   @ 32768 / 40960  (F2 A frags: T,  *256)
//   t2h/t2l: f16[16][2][64][8]  @ 49152 / 57344  (I1 A frags: Tt, *256)
//   y  : f32[1024][64][256] @ 65536   (aliased by g[1024][256][64] later)
//   xf : float2[16][64][32][32] @ 16842752
//   om : float2[16][64][32][32] @ 18939904

typedef _Float16 f16x8 __attribute__((ext_vector_type(8)));
typedef float f32x4 __attribute__((ext_vector_type(4)));

__device__ __forceinline__ void splitv(float s, _Float16& h, _Float16& l) {
    h = (_Float16)s;
    l = (_Float16)(s - (float)h);
}

// split two float4s (pre-scaled) into hi/lo f16x8 fragments
__device__ __forceinline__ void split8(float4 a, float4 b, float sc, f16x8& hv, f16x8& lv) {
    float v[8] = {a.x * sc, a.y * sc, a.z * sc, a.w * sc,
                  b.x * sc, b.y * sc, b.z * sc, b.w * sc};
#pragma unroll
    for (int q = 0; q < 8; ++q) {
        _Float16 h, l;
        splitv(v[q], h, l);
        hv[q] = h;
        lv[q] = l;
    }
}

__global__ __launch_bounds__(256) void k_tables(float* __restrict__ ws) {
    int idx = blockIdx.x * 256 + threadIdx.x;   // 0..8191
    int tab = idx >> 11, e = idx & 2047;
    int l = e & 63;
    const float STEP = 6.283185307179586f / 256.f;
    float s, c;
    _Float16* hb;
    _Float16* lb;
    if (tab == 0) { hb = (_Float16*)ws;               lb = (_Float16*)(ws + 8192); }
    else if (tab == 1) { hb = (_Float16*)(ws + 16384); lb = (_Float16*)(ws + 24576); }
    else if (tab == 2) { hb = (_Float16*)(ws + 32768); lb = (_Float16*)(ws + 40960); }
    else { hb = (_Float16*)(ws + 49152);               lb = (_Float16*)(ws + 57344); }
#pragma unroll
    for (int j = 0; j < 8; ++j) {
        float val;
        if (tab == 0) {          // e1: F1 B. col=2ky|re/im over w-DFT
            int nt = (e >> 6) & 3, kt = e >> 8;
            int col = nt * 16 + (l & 15);
            int ky = col >> 1;
            int k = kt * 32 + (l >> 4) * 8 + j;
            int t_ = (k * ky) & 255;
            sincosf((float)t_ * STEP, &s, &c);
            val = ((col & 1) ? -s : c) * 256.f;
        } else if (tab == 1) {   // e2: I2 B. row k even=cos, odd=-sin
            int nt = (e >> 6) & 15, kt = e >> 10;
            int w = nt * 16 + (l & 15);
            int k = kt * 32 + (l >> 4) * 8 + j;
            int ky = k >> 1;
            int t_ = (ky * w) & 255;
            sincosf((float)t_ * STEP, &s, &c);
            val = ((k & 1) ? -s : c) * 256.f;
        } else if (tab == 2) {   // t1: F2 A = T[kx][h]; m<32 cos, m>=32 sin
            int kt = (e >> 6) & 7, mt = e >> 9;
            int m = mt * 16 + (l & 15);
            int h = kt * 32 + (l >> 4) * 8 + j;
            int mm = (m < 32) ? m : (m - 32);
            int t_ = (mm * h) & 255;
            sincosf((float)t_ * STEP, &s, &c);
            val = ((m < 32) ? c : s) * 256.f;
        } else {                 // t2: I1 A = Tt[h][k]; k<32 cos, k>=32 sin
            int kt = (e >> 6) & 1, mt = e >> 7;
            int h = mt * 16 + (l & 15);
            int k = kt * 32 + (l >> 4) * 8 + j;
            int kk = (k < 32) ? k : (k - 32);
            int t_ = (kk * h) & 255;
            sincosf((float)t_ * STEP, &s, &c);
            val = ((k < 32) ? c : s) * 256.f;
        }
        _Float16 h16;
        _Float16 l16;
        splitv(val, h16, l16);
        hb[e * 8 + j] = h16;
        lb[e * 8 + j] = l16;
    }
}

// F1: rows (b,i,h) M=262144, K=256(w), N=64. Direct-frag A loads, no main-loop LDS.
// Epilogue: LDS transpose -> y stored f32 as [bi][col][h] (= Y_true).
__global__ __launch_bounds__(256) void k_f1(const float* __restrict__ x,
                                            const _Float16* __restrict__ e1h,
                                            const _Float16* __restrict__ e1l,
                                            float* __restrict__ yf) {
    __shared__ float Ls[128 * 66];
    int t = threadIdx.x, lane = t & 63, wv = t >> 6;
    long row0 = (long)blockIdx.x * 128;
    const float* xp0 = x + (row0 + wv * 32 + (lane & 15)) * 256 + (lane >> 4) * 8;
    const float* xp1 = xp0 + 16 * 256;
    f32x4 acc[2][4];
#pragma unroll
    for (int m = 0; m < 2; ++m)
#pragma unroll
        for (int n = 0; n < 4; ++n) acc[m][n] = (f32x4){0.f, 0.f, 0.f, 0.f};

    for (int kt = 0; kt < 8; ++kt) {
        float4 a00 = *(const float4*)(xp0 + kt * 32);
        float4 a01 = *(const float4*)(xp0 + kt * 32 + 4);
        float4 a10 = *(const float4*)(xp1 + kt * 32);
        float4 a11 = *(const float4*)(xp1 + kt * 32 + 4);
        f16x8 ah0, al0, ah1, al1;
        split8(a00, a01, 256.f, ah0, al0);
        split8(a10, a11, 256.f, ah1, al1);
#pragma unroll
        for (int n = 0; n < 4; ++n) {
            f16x8 bh = *(const f16x8*)(e1h + ((kt * 4 + n) * 64 + lane) * 8);
            f16x8 bl = *(const f16x8*)(e1l + ((kt * 4 + n) * 64 + lane) * 8);
            acc[0][n] = __builtin_amdgcn_mfma_f32_16x16x32_f16(ah0, bh, acc[0][n], 0, 0, 0);
            acc[0][n] = __builtin_amdgcn_mfma_f32_16x16x32_f16(al0, bh, acc[0][n], 0, 0, 0);
            acc[0][n] = __builtin_amdgcn_mfma_f32_16x16x32_f16(ah0, bl, acc[0][n], 0, 0, 0);
            acc[1][n] = __builtin_amdgcn_mfma_f32_16x16x32_f16(ah1, bh, acc[1][n], 0, 0, 0);
            acc[1][n] = __builtin_amdgcn_mfma_f32_16x16x32_f16(al1, bh, acc[1][n], 0, 0, 0);
            acc[1][n] = __builtin_amdgcn_mfma_f32_16x16x32_f16(ah1, bl, acc[1][n], 0, 0, 0);
        }
    }
    const float SCY = 1.f / 16777216.f;   // y = Y_true
#pragma unroll
    for (int m = 0; m < 2; ++m)
#pragma unroll
        for (int n = 0; n < 4; ++n)
#pragma unroll
            for (int r = 0; r < 4; ++r)
                Ls[(wv * 32 + m * 16 + (lane >> 4) * 4 + r) * 66 + n * 16 + (lane & 15)] =
                    acc[m][n][r] * SCY;
    __syncthreads();
    int col = t & 63, hg = t >> 6;
    long bi = row0 >> 8;
    int h0 = (int)(row0 & 255);
    float* yp = yf + bi * 16384 + (long)col * 256 + h0 + hg * 32;
#pragma unroll
    for (int sseg = 0; sseg < 4; ++sseg) {
        float4 v0, v1;
        v0.x = Ls[(hg * 32 + sseg * 8 + 0) * 66 + col];
        v0.y = Ls[(hg * 32 + sseg * 8 + 1) * 66 + col];
        v0.z = Ls[(hg * 32 + sseg * 8 + 2) * 66 + col];
        v0.w = Ls[(hg * 32 + sseg * 8 + 3) * 66 + col];
        v1.x = Ls[(hg * 32 + sseg * 8 + 4) * 66 + col];
        v1.y = Ls[(hg * 32 + sseg * 8 + 5) * 66 + col];
        v1.z = Ls[(hg * 32 + sseg * 8 + 6) * 66 + col];
        v1.w = Ls[(hg * 32 + sseg * 8 + 7) * 66 + col];
        *(float4*)(yp + sseg * 8) = v0;
        *(float4*)(yp + sseg * 8 + 4) = v1;
    }
}

// F2: per (b,i): C[64 kx'][64 col] = T(t1) * Y(f32, split at load x1024). 4-TERM.
__global__ __launch_bounds__(256) void k_f2(const _Float16* __restrict__ t1h,
                                            const _Float16* __restrict__ t1l,
                                            const float* __restrict__ yf,
                                            float2* __restrict__ xf) {
    __shared__ float Cs[64 * 65];
    int t = threadIdx.x, lane = t & 63, wv = t >> 6;
    long bi = blockIdx.x;
    const float* yb = yf + bi * 16384;
    f32x4 acc[4];
#pragma unroll
    for (int n = 0; n < 4; ++n) acc[n] = (f32x4){0.f, 0.f, 0.f, 0.f};

    for (int kt = 0; kt < 8; ++kt) {
        f16x8 ah = *(const f16x8*)(t1h + ((wv * 8 + kt) * 64 + lane) * 8);
        f16x8 al = *(const f16x8*)(t1l + ((wv * 8 + kt) * 64 + lane) * 8);
        int hoff = kt * 32 + (lane >> 4) * 8;
#pragma unroll
        for (int n = 0; n < 4; ++n) {
            int col = n * 16 + (lane & 15);
            const float* p = yb + col * 256 + hoff;
            float4 v0 = *(const float4*)p;
            float4 v1 = *(const float4*)(p + 4);
            f16x8 bh, bl;
            split8(v0, v1, 1024.f, bh, bl);
            acc[n] = __builtin_amdgcn_mfma_f32_16x16x32_f16(ah, bh, acc[n], 0, 0, 0);
            acc[n] = __builtin_amdgcn_mfma_f32_16x16x32_f16(al, bh, acc[n], 0, 0, 0);
            acc[n] = __builtin_amdgcn_mfma_f32_16x16x32_f16(ah, bl, acc[n], 0, 0, 0);
            acc[n] = __builtin_amdgcn_mfma_f32_16x16x32_f16(al, bl, acc[n], 0, 0, 0);
        }
    }
    const float SC = 1.f / 262144.f;   // 256 * 1024
#pragma unroll
    for (int n = 0; n < 4; ++n)
#pragma unroll
        for (int r = 0; r < 4; ++r)
            Cs[(wv * 16 + (lane >> 4) * 4 + r) * 65 + n * 16 + (lane & 15)] = acc[n][r] * SC;
    __syncthreads();
#pragma unroll
    for (int n = 0; n < 4; ++n) {
        int idx = t + n * 256;
        int kx = idx >> 5, ky = idx & 31;
        float re = Cs[kx * 65 + 2 * ky]     + Cs[(kx + 32) * 65 + 2 * ky + 1];
        float im = Cs[kx * 65 + 2 * ky + 1] - Cs[(kx + 32) * 65 + 2 * ky];
        xf[bi * 1024 + kx * 32 + ky] = make_float2(re, im);
    }
}

// M: per (b,kx): om[b,o,kx,ky] = sum_i xf[b,i,kx,ky] * (wr+i*wi)  (fp32, unchanged)
__global__ __launch_bounds__(256) void k_mix(const float* __restrict__ wr,
                                             const float* __restrict__ wi,
                                             const float2* __restrict__ xf,
                                             float2* __restrict__ om) {
    __shared__ float2 xs[64 * 32];
    int t = threadIdx.x;
    int b = blockIdx.x >> 5, kx = blockIdx.x & 31;
#pragma unroll
    for (int n = 0; n < 8; ++n) {
        int i2 = t + n * 256;
        int i = i2 >> 5, ky = i2 & 31;
        xs[i2] = xf[(long)(b * 64 + i) * 1024 + kx * 32 + ky];
    }
    __syncthreads();
    int ky = t & 31, og = t >> 5;
    float ar[8], ai[8];
#pragma unroll
    for (int j = 0; j < 8; ++j) { ar[j] = 0.f; ai[j] = 0.f; }
    const float* wrb = wr + kx * 32 + ky;
    const float* wib = wi + kx * 32 + ky;
    for (int i = 0; i < 64; ++i) {
        float2 xv = xs[i * 32 + ky];
#pragma unroll
        for (int j = 0; j < 8; ++j) {
            int o = og * 8 + j;
            long woff = (long)(i * 64 + o) * 1024;
            float wrv = wrb[woff], wiv = wib[woff];
            ar[j] = fmaf(xv.x, wrv, fmaf(-xv.y, wiv, ar[j]));
            ai[j] = fmaf(xv.x, wiv, fmaf(xv.y, wrv, ai[j]));
        }
    }
    float2* omb = om + (long)(b * 64) * 1024 + kx * 32 + ky;
#pragma unroll
    for (int j = 0; j < 8; ++j) {
        int o = og * 8 + j;
        omb[(long)o * 1024] = make_float2(ar[j], ai[j]);
    }
}

// I1: per (b,o): C[256 h][64 col] = Tt(t2) * Bm(om x4096).  4-TERM.
// g stored f32 row-major, = herm * z.
__global__ __launch_bounds__(256) void k_i1(const _Float16* __restrict__ t2h,
                                            const _Float16* __restrict__ t2l,
                                            const float2* __restrict__ om,
                                            float* __restrict__ gf) {
    __shared__ __align__(16) _Float16 Bsh[64 * 88];   // [n][k], stride 88 halves
    __shared__ __align__(16) _Float16 Bsl[64 * 88];
    int t = threadIdx.x, lane = t & 63, wv = t >> 6;
    long bo = blockIdx.x;
    const float2* omb = om + bo * 1024;
#pragma unroll
    for (int n = 0; n < 4; ++n) {
        int e = t + n * 256;           // = kx*32 + ky
        int kx = e >> 5, ky = e & 31;
        float2 v = omb[e];
        float re = v.x * 4096.f, im = v.y * 4096.f;
        _Float16 rh, rl, ih, il;
        splitv(re, rh, rl);
        splitv(im, ih, il);
        Bsh[(2 * ky) * 88 + kx] = rh;          Bsl[(2 * ky) * 88 + kx] = rl;
        Bsh[(2 * ky + 1) * 88 + kx] = ih;      Bsl[(2 * ky + 1) * 88 + kx] = il;
        Bsh[(2 * ky) * 88 + kx + 32] = -ih;    Bsl[(2 * ky) * 88 + kx + 32] = -il;
        Bsh[(2 * ky + 1) * 88 + kx + 32] = rh; Bsl[(2 * ky + 1) * 88 + kx + 32] = rl;
    }
    __syncthreads();
    f32x4 acc[4][4];
#pragma unroll
    for (int mi = 0; mi < 4; ++mi)
#pragma unroll
        for (int n = 0; n < 4; ++n) acc[mi][n] = (f32x4){0.f, 0.f, 0.f, 0.f};
#pragma unroll
    for (int mi = 0; mi < 4; ++mi) {
        int mt = wv * 4 + mi;
#pragma unroll
        for (int kt = 0; kt < 2; ++kt) {
            f16x8 ah = *(const f16x8*)(t2h + ((mt * 2 + kt) * 64 + lane) * 8);
            f16x8 al = *(const f16x8*)(t2l + ((mt * 2 + kt) * 64 + lane) * 8);
            int koff = kt * 32 + (lane >> 4) * 8;
#pragma unroll
            for (int n = 0; n < 4; ++n) {
                int col = n * 16 + (lane & 15);
                f16x8 bh = *(const f16x8*)&Bsh[col * 88 + koff];
                f16x8 bl = *(const f16x8*)&Bsl[col * 88 + koff];
                acc[mi][n] = __builtin_amdgcn_mfma_f32_16x16x32_f16(ah, bh, acc[mi][n], 0, 0, 0);
                acc[mi][n] = __builtin_amdgcn_mfma_f32_16x16x32_f16(al, bh, acc[mi][n], 0, 0, 0);
                acc[mi][n] = __builtin_amdgcn_mfma_f32_16x16x32_f16(ah, bl, acc[mi][n], 0, 0, 0);
                acc[mi][n] = __builtin_amdgcn_mfma_f32_16x16x32_f16(al, bl, acc[mi][n], 0, 0, 0);
            }
        }
    }
#pragma unroll
    for (int mi = 0; mi < 4; ++mi)
#pragma unroll
        for (int n = 0; n < 4; ++n) {
            int col = n * 16 + (lane & 15);
            float sa = ((col >> 1) == 0 ? 1.f : 2.f) * (1.f / 1048576.f);
#pragma unroll
            for (int r = 0; r < 4; ++r) {
                int h = (wv * 4 + mi) * 16 + (lane >> 4) * 4 + r;
                gf[bo * 16384 + h * 64 + col] = acc[mi][n][r] * sa;
            }
        }
}

// I2: out[M=262144][256] = G[M][64] * E2u[64][256] /256.  Split-at-load x256, 3-term, no LDS.
__global__ __launch_bounds__(256) void k_i2(const float* __restrict__ gf,
                                            const _Float16* __restrict__ e2h,
                                            const _Float16* __restrict__ e2l,
                                            float* __restrict__ out) {
    int t = threadIdx.x, lane = t & 63, wv = t >> 6;
    long row0 = (long)blockIdx.x * 32;
    const float* gp0 = gf + (row0 + (lane & 15)) * 64 + (lane >> 4) * 8;
    f32x4 acc[2][4];
#pragma unroll
    for (int m = 0; m < 2; ++m)
#pragma unroll
        for (int n = 0; n < 4; ++n) acc[m][n] = (f32x4){0.f, 0.f, 0.f, 0.f};
#pragma unroll
    for (int kt = 0; kt < 2; ++kt) {
        float4 v00 = *(const float4*)(gp0 + kt * 32);
        float4 v01 = *(const float4*)(gp0 + kt * 32 + 4);
        float4 v10 = *(const float4*)(gp0 + 16 * 64 + kt * 32);
        float4 v11 = *(const float4*)(gp0 + 16 * 64 + kt * 32 + 4);
        f16x8 ah0, al0, ah1, al1;
        split8(v00, v01, 256.f, ah0, al0);
        split8(v10, v11, 256.f, ah1, al1);
#pragma unroll
        for (int n = 0; n < 4; ++n) {
            f16x8 bh = *(const f16x8*)(e2h + ((kt * 16 + wv * 4 + n) * 64 + lane) * 8);
            f16x8 bl = *(const f16x8*)(e2l + ((kt * 16 + wv * 4 + n) * 64 + lane) * 8);
            acc[0][n] = __builtin_amdgcn_mfma_f32_16x16x32_f16(ah0, bh, acc[0][n], 0, 0, 0);
            acc[0][n] = __builtin_amdgcn_mfma_f32_16x16x32_f16(al0, bh, acc[0][n], 0, 0, 0);
            acc[0][n] = __builtin_amdgcn_mfma_f32_16x16x32_f16(ah0, bl, acc[0][n], 0, 0, 0);
            acc[1][n] = __builtin_amdgcn_mfma_f32_16x16x32_f16(ah1, bh, acc[1][n], 0, 0, 0);
            acc[1][n] = __builtin_amdgcn_mfma_f32_16x16x32_f16(al1, bh, acc[1][n], 0, 0, 0);
            acc[1][n] = __builtin_amdgcn_mfma_f32_16x16x32_f16(ah1, bl, acc[1][n], 0, 0, 0);
        }
    }
    const float SC = 1.f / 16777216.f;   // 256(g) * 256(e2) * 256(DFT norm)
#pragma unroll
    for (int m = 0; m < 2; ++m)
#pragma unroll
        for (int n = 0; n < 4; ++n)
#pragma unroll
            for (int r = 0; r < 4; ++r) {
                long row = row0 + m * 16 + (lane >> 4) * 4 + r;
                out[row * 256 + wv * 64 + n * 16 + (lane & 15)] = acc[m][n][r] * SC;
            }
}

extern "C" void kernel_launch(void* const* d_in, const int* in_sizes, int n_in,
                              void* d_out, int out_size, void* d_ws, size_t ws_size,
                              hipStream_t stream) {
    const float* x  = (const float*)d_in[0];
    const float* wr = (const float*)d_in[1];
    const float* wi = (const float*)d_in[2];
    float* out = (float*)d_out;
    float* ws = (float*)d_ws;

    const _Float16* e1h = (const _Float16*)ws;
    const _Float16* e1l = (const _Float16*)(ws + 8192);
    const _Float16* e2h = (const _Float16*)(ws + 16384);
    const _Float16* e2l = (const _Float16*)(ws + 24576);
    const _Float16* t1h = (const _Float16*)(ws + 32768);
    const _Float16* t1l = (const _Float16*)(ws + 40960);
    const _Float16* t2h = (const _Float16*)(ws + 49152);
    const _Float16* t2l = (const _Float16*)(ws + 57344);
    float* yf = ws + 65536;              // 16,777,216 floats
    float* xf = ws + 16842752;
    float* om = ws + 18939904;
    float* gf = yf;   // alias (y dead after k_f2)

    hipLaunchKernelGGL(k_tables, dim3(32),   dim3(256), 0, stream, ws);
    hipLaunchKernelGGL(k_f1,     dim3(2048), dim3(256), 0, stream, x, e1h, e1l, yf);
    hipLaunchKernelGGL(k_f2,     dim3(1024), dim3(256), 0, stream, t1h, t1l, yf, (float2*)xf);
    hipLaunchKernelGGL(k_mix,    dim3(512),  dim3(256), 0, stream, wr, wi, (const float2*)xf, (float2*)om);
    hipLaunchKernelGGL(k_i1,     dim3(1024), dim3(256), 0, stream, t2h, t2l, (const float2*)om, gf);
    hipLaunchKernelGGL(k_i2,     dim3(8192), dim3(256), 0, stream, gf, e2h, e2l, out);
}